// Round 2
// baseline (791.013 us; speedup 1.0000x reference)
//
#include <hip/hip_runtime.h>

#define N_PTS 300000
#define NPAD  300032   // 1172 blocks * 256 pts

typedef _Float16 f16;
typedef _Float16 f16x8 __attribute__((ext_vector_type(8)));
typedef float    f32x4 __attribute__((ext_vector_type(4)));

__device__ __forceinline__ f16 f2h(float x) { return (f16)x; }

// ---------------------------------------------------------------------------
// prep: features -> fp16 (zero-padded tail rows), weights -> fp16 transposed
// Wt1/Wt3: [k][d][c] from W[k][c][d];  Wt2b: [k][d][c2];  Wt2a: [d2][c]
// ---------------------------------------------------------------------------
__global__ __launch_bounds__(256) void k_prep(
    const float* __restrict__ feat, const float* __restrict__ W1,
    const float* __restrict__ W2a,  const float* __restrict__ W2b,
    const float* __restrict__ W3,
    f16* __restrict__ featf, f16* __restrict__ Wt1, f16* __restrict__ Wt2a,
    f16* __restrict__ Wt2b, f16* __restrict__ Wt3)
{
    long i = (long)blockIdx.x * 256 + threadIdx.x;
    const long FE = (long)NPAD * 64;
    if (i < FE) {
        long n = i >> 6;
        featf[i] = (n < N_PTS) ? f2h(feat[i]) : (f16)0.f;
    } else {
        int j = (int)(i - FE);
        if (j < 36864) {                       // Wt1
            int k = j >> 12, rem = j & 4095, d = rem >> 6, c = rem & 63;
            Wt1[j] = f2h(W1[(k << 12) + (c << 6) + d]);
        } else if (j < 73728) {                // Wt3
            int jj = j - 36864;
            int k = jj >> 12, rem = jj & 4095, d = rem >> 6, c = rem & 63;
            Wt3[jj] = f2h(W3[(k << 12) + (c << 6) + d]);
        } else if (j < 73728 + 18432) {        // Wt2b [k][d][c2]
            int jj = j - 73728;
            int k = jj >> 11, rem = jj & 2047, d = rem >> 5, c2 = rem & 31;
            Wt2b[jj] = f2h(W2b[k * 2048 + c2 * 64 + d]);
        } else if (j < 73728 + 18432 + 2048) { // Wt2a [d2][c]
            int jj = j - 73728 - 18432;
            int d2 = jj >> 6, c = jj & 63;
            Wt2a[jj] = f2h(W2a[c * 32 + d2]);
        }
    }
}

// ---------------------------------------------------------------------------
// bottleneck: h = relu(bn2a(feat @ W2a))  [N,32] fp16.  64 pts/wave.
// ---------------------------------------------------------------------------
__global__ __launch_bounds__(256) void k_bottleneck(
    const f16* __restrict__ featf, const f16* __restrict__ Wt2a,
    const float* __restrict__ s2a, const float* __restrict__ b2a,
    f16* __restrict__ hf)
{
    int lane = threadIdx.x & 63, wave = threadIdx.x >> 6;
    int n0 = (blockIdx.x * 4 + wave) * 64;
    int ln = lane & 15, q = lane >> 4;
    f32x4 acc[4][2];
    for (int mt = 0; mt < 4; mt++) for (int nt = 0; nt < 2; nt++)
        acc[mt][nt] = (f32x4){0.f, 0.f, 0.f, 0.f};
    for (int ks = 0; ks < 2; ks++) {
        f16x8 a[4];
#pragma unroll
        for (int mt = 0; mt < 4; mt++)
            a[mt] = *(const f16x8*)(featf + ((n0 + mt * 16 + ln) * 64 + ks * 32 + q * 8));
#pragma unroll
        for (int nt = 0; nt < 2; nt++) {
            f16x8 b = *(const f16x8*)(Wt2a + ((nt * 16 + ln) * 64 + ks * 32 + q * 8));
#pragma unroll
            for (int mt = 0; mt < 4; mt++)
                acc[mt][nt] = __builtin_amdgcn_mfma_f32_16x16x32_f16(a[mt], b, acc[mt][nt], 0, 0, 0);
        }
    }
#pragma unroll
    for (int nt = 0; nt < 2; nt++) {
        int ch = nt * 16 + ln;
        float s = s2a[ch], bb = b2a[ch];
#pragma unroll
        for (int mt = 0; mt < 4; mt++)
#pragma unroll
            for (int r = 0; r < 4; r++) {
                int n = n0 + mt * 16 + q * 4 + r;
                if (n < N_PTS)
                    hf[n * 32 + ch] = f2h(fmaxf(acc[mt][nt][r] * s + bb, 0.f));
            }
    }
}

// ---------------------------------------------------------------------------
// one sparse-conv path: D[64 pts][64 ch] = sum_k gather_k(src) @ Wt[k]
// wave-private LDS staging, B-frags from global, BN+ReLU epilogue,
// ms store (fp16) + per-channel max -> atomicMax(pooled)
// ---------------------------------------------------------------------------
template <int CIN>
__device__ __forceinline__ void conv_path(
    const f16* __restrict__ src, const f16* __restrict__ Wt,
    const int* __restrict__ nbr, f16* __restrict__ Asw,
    int lane, int n0,
    const float* __restrict__ bns, const float* __restrict__ bnb,
    f16* __restrict__ msf, int colBase, float* __restrict__ pooled)
{
    constexpr int LS   = CIN + 8;        // LDS row stride (halves)
    constexpr int CPR  = CIN / 8;        // 16B chunks per row
    constexpr int REPS = 64 * CPR / 64;  // staging wave-iterations
    constexpr int KS   = CIN / 32;
    int ln = lane & 15, q = lane >> 4;
    f32x4 acc[4][4];
    for (int mt = 0; mt < 4; mt++) for (int nt = 0; nt < 4; nt++)
        acc[mt][nt] = (f32x4){0.f, 0.f, 0.f, 0.f};

    for (int k = 0; k < 9; k++) {
        __syncthreads();  // previous iter's frag reads done before overwrite
        const int* nb = nbr + k * N_PTS;
#pragma unroll
        for (int rep = 0; rep < REPS; rep++) {
            int flat = rep * 64 + lane;
            int row = flat / CPR, chunk = flat % CPR;
            int nn = n0 + row;
            int idx = (nn < N_PTS) ? nb[nn] : -1;
            uint4 v = make_uint4(0u, 0u, 0u, 0u);
            if (idx >= 0) v = *(const uint4*)(src + (idx * CIN + chunk * 8));
            *(uint4*)(&Asw[row * LS + chunk * 8]) = v;
        }
        __syncthreads();
        const f16* Wk = Wt + k * CIN * 64;
#pragma unroll
        for (int ks = 0; ks < KS; ks++) {
            f16x8 a[4];
#pragma unroll
            for (int mt = 0; mt < 4; mt++)
                a[mt] = *(const f16x8*)(&Asw[(mt * 16 + ln) * LS + ks * 32 + q * 8]);
#pragma unroll
            for (int nt = 0; nt < 4; nt++) {
                f16x8 b = *(const f16x8*)(Wk + ((nt * 16 + ln) * CIN + ks * 32 + q * 8));
#pragma unroll
                for (int mt = 0; mt < 4; mt++)
                    acc[mt][nt] = __builtin_amdgcn_mfma_f32_16x16x32_f16(a[mt], b, acc[mt][nt], 0, 0, 0);
            }
        }
    }
    // epilogue: BN + ReLU, store ms fp16, channel max -> pooled
#pragma unroll
    for (int nt = 0; nt < 4; nt++) {
        int ch = colBase + nt * 16 + ln;
        float s = bns[nt * 16 + ln], bb = bnb[nt * 16 + ln];
        float cmax = 0.f;
#pragma unroll
        for (int mt = 0; mt < 4; mt++)
#pragma unroll
            for (int r = 0; r < 4; r++) {
                int n = n0 + mt * 16 + q * 4 + r;   // always < NPAD
                float v = fmaxf(acc[mt][nt][r] * s + bb, 0.f);
                msf[n * 192 + ch] = f2h(v);
                if (n < N_PTS) cmax = fmaxf(cmax, v);
            }
        cmax = fmaxf(cmax, __shfl_xor(cmax, 16));
        cmax = fmaxf(cmax, __shfl_xor(cmax, 32));
        if (q == 0) atomicMax((int*)(pooled + ch), __float_as_int(cmax));
    }
}

__global__ __launch_bounds__(256) void k_conv(
    const f16* __restrict__ featf, const f16* __restrict__ hf,
    const f16* __restrict__ Wt1, const f16* __restrict__ Wt2b, const f16* __restrict__ Wt3,
    const int* __restrict__ nbr1, const int* __restrict__ nbr2,
    const float* __restrict__ bn1_s, const float* __restrict__ bn1_b,
    const float* __restrict__ bn2b_s, const float* __restrict__ bn2b_b,
    const float* __restrict__ bn3_s, const float* __restrict__ bn3_b,
    f16* __restrict__ msf, float* __restrict__ pooled)
{
    __shared__ __align__(16) f16 As[4][64 * 72];
    int lane = threadIdx.x & 63, wave = threadIdx.x >> 6;
    int n0 = (blockIdx.x * 4 + wave) * 64;
    f16* Asw = As[wave];
    conv_path<64>(featf, Wt1,  nbr1, Asw, lane, n0, bn1_s,  bn1_b,  msf, 0,   pooled);
    conv_path<32>(hf,    Wt2b, nbr1, Asw, lane, n0, bn2b_s, bn2b_b, msf, 64,  pooled);
    conv_path<64>(featf, Wt3,  nbr2, Asw, lane, n0, bn3_s,  bn3_b,  msf, 128, pooled);
}

// ---------------------------------------------------------------------------
// attention MLP (1 block) + fold attn*Wf -> Wfst[d][j] fp16
// A1_w: [192,16], A2_w: [16,192]  (COUT//4 == 16)
// ---------------------------------------------------------------------------
__global__ __launch_bounds__(256) void k_attn(
    const float* __restrict__ pooled,
    const float* __restrict__ A1w, const float* __restrict__ A1b,
    const float* __restrict__ A2w, const float* __restrict__ A2b,
    const float* __restrict__ Wf, f16* __restrict__ Wfst)
{
    __shared__ float sp[192], sa1[16], sattn[192];
    int t = threadIdx.x;
    if (t < 192) sp[t] = pooled[t];
    __syncthreads();
    if (t < 16) {
        float acc = A1b[t];
        for (int i = 0; i < 192; i++) acc += sp[i] * A1w[i * 16 + t];
        sa1[t] = fmaxf(acc, 0.f);
    }
    __syncthreads();
    if (t < 192) {
        float acc = A2b[t];
        for (int i = 0; i < 16; i++) acc += sa1[i] * A2w[i * 192 + t];
        sattn[t] = 1.f / (1.f + expf(-acc));
    }
    __syncthreads();
    for (int i = t; i < 192 * 64; i += 256) {
        int d = i / 192, j = i % 192;
        Wfst[i] = f2h(Wf[j * 64 + d] * sattn[j]);
    }
}

// ---------------------------------------------------------------------------
// fusion: out = relu(bnf( ms @ (attn*Wf) ))  fp32 out
// ---------------------------------------------------------------------------
__global__ __launch_bounds__(256) void k_fuse(
    const f16* __restrict__ msf, const f16* __restrict__ Wfst,
    const float* __restrict__ sf, const float* __restrict__ bf_,
    float* __restrict__ out)
{
    __shared__ __align__(16) f16 As[4][64 * 72];
    int lane = threadIdx.x & 63, wave = threadIdx.x >> 6;
    f16* Asw = As[wave];
    int n0 = (blockIdx.x * 4 + wave) * 64;
    int ln = lane & 15, q = lane >> 4;
    f32x4 acc[4][4];
    for (int mt = 0; mt < 4; mt++) for (int nt = 0; nt < 4; nt++)
        acc[mt][nt] = (f32x4){0.f, 0.f, 0.f, 0.f};
    for (int kc = 0; kc < 3; kc++) {
        __syncthreads();
#pragma unroll
        for (int rep = 0; rep < 8; rep++) {
            int flat = rep * 64 + lane;
            int row = flat >> 3, chunk = flat & 7;
            uint4 v = *(const uint4*)(msf + ((n0 + row) * 192 + kc * 64 + chunk * 8));
            *(uint4*)(&Asw[row * 72 + chunk * 8]) = v;
        }
        __syncthreads();
#pragma unroll
        for (int ks = 0; ks < 2; ks++) {
            f16x8 a[4];
#pragma unroll
            for (int mt = 0; mt < 4; mt++)
                a[mt] = *(const f16x8*)(&Asw[(mt * 16 + ln) * 72 + ks * 32 + q * 8]);
#pragma unroll
            for (int nt = 0; nt < 4; nt++) {
                f16x8 b = *(const f16x8*)(Wfst + ((nt * 16 + ln) * 192 + kc * 64 + ks * 32 + q * 8));
#pragma unroll
                for (int mt = 0; mt < 4; mt++)
                    acc[mt][nt] = __builtin_amdgcn_mfma_f32_16x16x32_f16(a[mt], b, acc[mt][nt], 0, 0, 0);
            }
        }
    }
#pragma unroll
    for (int nt = 0; nt < 4; nt++) {
        int ch = nt * 16 + ln;
        float s = sf[ch], bb = bf_[ch];
#pragma unroll
        for (int mt = 0; mt < 4; mt++)
#pragma unroll
            for (int r = 0; r < 4; r++) {
                int n = n0 + mt * 16 + q * 4 + r;
                if (n < N_PTS)
                    out[n * 64 + ch] = fmaxf(acc[mt][nt][r] * s + bb, 0.f);
            }
    }
}

// ---------------------------------------------------------------------------
extern "C" void kernel_launch(void* const* d_in, const int* in_sizes, int n_in,
                              void* d_out, int out_size, void* d_ws, size_t ws_size,
                              hipStream_t stream)
{
    const float* features = (const float*)d_in[0];
    const float* W1     = (const float*)d_in[1];
    const float* bn1_s  = (const float*)d_in[2];
    const float* bn1_b  = (const float*)d_in[3];
    const float* W2a    = (const float*)d_in[4];
    const float* bn2a_s = (const float*)d_in[5];
    const float* bn2a_b = (const float*)d_in[6];
    const float* W2b    = (const float*)d_in[7];
    const float* bn2b_s = (const float*)d_in[8];
    const float* bn2b_b = (const float*)d_in[9];
    const float* W3     = (const float*)d_in[10];
    const float* bn3_s  = (const float*)d_in[11];
    const float* bn3_b  = (const float*)d_in[12];
    const float* A1w    = (const float*)d_in[13];
    const float* A1b    = (const float*)d_in[14];
    const float* A2w    = (const float*)d_in[15];
    const float* A2b    = (const float*)d_in[16];
    const float* Wf     = (const float*)d_in[17];
    const float* bnf_s  = (const float*)d_in[18];
    const float* bnf_b  = (const float*)d_in[19];
    const int*   nbr1   = (const int*)d_in[20];
    const int*   nbr2   = (const int*)d_in[21];

    char* ws = (char*)d_ws;
    size_t off = 0;
    f16* featf = (f16*)(ws + off); off += (size_t)NPAD * 64 * 2;
    f16* hf    = (f16*)(ws + off); off += (size_t)NPAD * 32 * 2;
    f16* msf   = (f16*)(ws + off); off += (size_t)NPAD * 192 * 2;
    f16* Wt1   = (f16*)(ws + off); off += 9 * 64 * 64 * 2;
    f16* Wt3   = (f16*)(ws + off); off += 9 * 64 * 64 * 2;
    f16* Wt2b  = (f16*)(ws + off); off += 9 * 32 * 64 * 2;
    f16* Wt2a  = (f16*)(ws + off); off += 32 * 64 * 2;
    f16* Wfst  = (f16*)(ws + off); off += 192 * 64 * 2;
    float* pooled = (float*)(ws + off); off += 256 * 4;

    hipMemsetAsync(pooled, 0, 192 * sizeof(float), stream);

    const long FE = (long)NPAD * 64;
    int prep_blocks = (int)((FE + 94208 + 255) / 256);
    k_prep<<<prep_blocks, 256, 0, stream>>>(features, W1, W2a, W2b, W3,
                                            featf, Wt1, Wt2a, Wt2b, Wt3);
    k_bottleneck<<<NPAD / 256, 256, 0, stream>>>(featf, Wt2a, bn2a_s, bn2a_b, hf);
    k_conv<<<NPAD / 256, 256, 0, stream>>>(featf, hf, Wt1, Wt2b, Wt3, nbr1, nbr2,
                                           bn1_s, bn1_b, bn2b_s, bn2b_b, bn3_s, bn3_b,
                                           msf, pooled);
    k_attn<<<1, 256, 0, stream>>>(pooled, A1w, A1b, A2w, A2b, Wf, Wfst);
    k_fuse<<<NPAD / 256, 256, 0, stream>>>(msf, Wfst, bnf_s, bnf_b, (float*)d_out);
}

// Round 3
// 598.681 us; speedup vs baseline: 1.3213x; 1.3213x over previous
//
#include <hip/hip_runtime.h>

#define N_PTS 300000
#define NPAD  300032   // 1172 blocks * 256 pts

typedef _Float16 f16;
typedef _Float16 f16x8 __attribute__((ext_vector_type(8)));
typedef float    f32x4 __attribute__((ext_vector_type(4)));

__device__ __forceinline__ f16 f2h(float x) { return (f16)x; }

union u4f16 { uint4 u; f16x8 h; };

// ---------------------------------------------------------------------------
// prep: features -> fp16 (vectorized, zero-padded tail rows), weights -> fp16
// transposed.  Wt1/Wt3: [k][d][c]; Wt2b: [k][d][c2]; Wt2a: [d2][c]
// ---------------------------------------------------------------------------
__global__ __launch_bounds__(256) void k_prep(
    const float* __restrict__ feat, const float* __restrict__ W1,
    const float* __restrict__ W2a,  const float* __restrict__ W2b,
    const float* __restrict__ W3,
    f16* __restrict__ featf, f16* __restrict__ Wt1, f16* __restrict__ Wt2a,
    f16* __restrict__ Wt2b, f16* __restrict__ Wt3)
{
    long i = (long)blockIdx.x * 256 + threadIdx.x;
    const long FV = (long)NPAD * 8;          // 8-element chunks of features
    if (i < FV) {
        long n = i >> 3; int c8 = (int)(i & 7) * 8;
        u4f16 v;
        if (n < N_PTS) {
            const float* p = feat + n * 64 + c8;
#pragma unroll
            for (int j = 0; j < 8; j++) v.h[j] = f2h(p[j]);
        } else {
            v.u = make_uint4(0u, 0u, 0u, 0u);
        }
        *(uint4*)(featf + n * 64 + c8) = v.u;
    } else {
        int j = (int)(i - FV);
        if (j < 36864) {                       // Wt1
            int k = j >> 12, rem = j & 4095, d = rem >> 6, c = rem & 63;
            Wt1[j] = f2h(W1[(k << 12) + (c << 6) + d]);
        } else if (j < 73728) {                // Wt3
            int jj = j - 36864;
            int k = jj >> 12, rem = jj & 4095, d = rem >> 6, c = rem & 63;
            Wt3[jj] = f2h(W3[(k << 12) + (c << 6) + d]);
        } else if (j < 73728 + 18432) {        // Wt2b [k][d][c2]
            int jj = j - 73728;
            int k = jj >> 11, rem = jj & 2047, d = rem >> 5, c2 = rem & 31;
            Wt2b[jj] = f2h(W2b[k * 2048 + c2 * 64 + d]);
        } else if (j < 73728 + 18432 + 2048) { // Wt2a [d2][c]
            int jj = j - 73728 - 18432;
            int d2 = jj >> 6, c = jj & 63;
            Wt2a[jj] = f2h(W2a[c * 32 + d2]);
        }
    }
}

// ---------------------------------------------------------------------------
// bottleneck: h = relu(bn2a(feat @ W2a))  [N,32] fp16.  64 pts/wave.
// ---------------------------------------------------------------------------
__global__ __launch_bounds__(256) void k_bottleneck(
    const f16* __restrict__ featf, const f16* __restrict__ Wt2a,
    const float* __restrict__ s2a, const float* __restrict__ b2a,
    f16* __restrict__ hf)
{
    int lane = threadIdx.x & 63, wave = threadIdx.x >> 6;
    int n0 = (blockIdx.x * 4 + wave) * 64;
    int ln = lane & 15, q = lane >> 4;
    f32x4 acc[4][2];
    for (int mt = 0; mt < 4; mt++) for (int nt = 0; nt < 2; nt++)
        acc[mt][nt] = (f32x4){0.f, 0.f, 0.f, 0.f};
#pragma unroll
    for (int ks = 0; ks < 2; ks++) {
        f16x8 a[4];
#pragma unroll
        for (int mt = 0; mt < 4; mt++)
            a[mt] = *(const f16x8*)(featf + ((n0 + mt * 16 + ln) * 64 + ks * 32 + q * 8));
#pragma unroll
        for (int nt = 0; nt < 2; nt++) {
            f16x8 b = *(const f16x8*)(Wt2a + ((nt * 16 + ln) * 64 + ks * 32 + q * 8));
#pragma unroll
            for (int mt = 0; mt < 4; mt++)
                acc[mt][nt] = __builtin_amdgcn_mfma_f32_16x16x32_f16(a[mt], b, acc[mt][nt], 0, 0, 0);
        }
    }
#pragma unroll
    for (int nt = 0; nt < 2; nt++) {
        int ch = nt * 16 + ln;
        float s = s2a[ch], bb = b2a[ch];
#pragma unroll
        for (int mt = 0; mt < 4; mt++)
#pragma unroll
            for (int r = 0; r < 4; r++) {
                int n = n0 + mt * 16 + q * 4 + r;
                if (n < N_PTS)
                    hf[n * 32 + ch] = f2h(fmaxf(acc[mt][nt][r] * s + bb, 0.f));
            }
    }
}

// ---------------------------------------------------------------------------
// sparse-conv path, DIRECT gather (no LDS, no barriers).
// A-fragment = 16B contiguous slice of gathered row: src[idx*CIN + ks*32+q*8].
// Pipeline: idx prefetched 2 taps ahead, row gathers 1 tap ahead; the
// zero-select for idx<0 is applied at consume time so the vmcnt wait lands
// after the previous tap's MFMA block.
// ---------------------------------------------------------------------------
template <int CIN>
__device__ __forceinline__ void conv_path(
    const f16* __restrict__ src, const f16* __restrict__ Wt,
    const int* __restrict__ nbr,
    int lane, int n0,
    const float* __restrict__ bns, const float* __restrict__ bnb,
    f16* __restrict__ msf, int colBase, float* __restrict__ pooled)
{
    constexpr int KS = CIN / 32;
    int ln = lane & 15, q = lane >> 4;
    f32x4 acc[4][4];
    for (int mt = 0; mt < 4; mt++) for (int nt = 0; nt < 4; nt++)
        acc[mt][nt] = (f32x4){0.f, 0.f, 0.f, 0.f};

    int  idx0[4], idx1[4];
    uint4 raw0[4][KS];

#pragma unroll
    for (int mt = 0; mt < 4; mt++) {
        int nn = n0 + mt * 16 + ln;
        idx0[mt] = (nn < N_PTS) ? nbr[nn] : -1;
        idx1[mt] = (nn < N_PTS) ? nbr[N_PTS + nn] : -1;
    }
#pragma unroll
    for (int mt = 0; mt < 4; mt++) {
        long b = (long)(idx0[mt] < 0 ? 0 : idx0[mt]) * CIN;
#pragma unroll
        for (int ks = 0; ks < KS; ks++)
            raw0[mt][ks] = *(const uint4*)(src + b + ks * 32 + q * 8);
    }

#pragma unroll
    for (int k = 0; k < 9; k++) {
        int  idx2[4];
        uint4 raw1[4][KS];
        if (k < 7) {
            const int* nb2 = nbr + (k + 2) * N_PTS;
#pragma unroll
            for (int mt = 0; mt < 4; mt++) {
                int nn = n0 + mt * 16 + ln;
                idx2[mt] = (nn < N_PTS) ? nb2[nn] : -1;
            }
        }
        if (k < 8) {
#pragma unroll
            for (int mt = 0; mt < 4; mt++) {
                long b = (long)(idx1[mt] < 0 ? 0 : idx1[mt]) * CIN;
#pragma unroll
                for (int ks = 0; ks < KS; ks++)
                    raw1[mt][ks] = *(const uint4*)(src + b + ks * 32 + q * 8);
            }
        }
        // consume tap k: select-zero then MFMA
        f16x8 a[4][KS];
#pragma unroll
        for (int mt = 0; mt < 4; mt++) {
#pragma unroll
            for (int ks = 0; ks < KS; ks++) {
                u4f16 v; v.u = raw0[mt][ks];
                if (idx0[mt] < 0) v.u = make_uint4(0u, 0u, 0u, 0u);
                a[mt][ks] = v.h;
            }
        }
        const f16* Wk = Wt + k * CIN * 64;
#pragma unroll
        for (int ks = 0; ks < KS; ks++) {
#pragma unroll
            for (int nt = 0; nt < 4; nt++) {
                f16x8 b = *(const f16x8*)(Wk + ((nt * 16 + ln) * CIN + ks * 32 + q * 8));
#pragma unroll
                for (int mt = 0; mt < 4; mt++)
                    acc[mt][nt] = __builtin_amdgcn_mfma_f32_16x16x32_f16(a[mt][ks], b, acc[mt][nt], 0, 0, 0);
            }
        }
        // rotate pipeline
#pragma unroll
        for (int mt = 0; mt < 4; mt++) {
            idx0[mt] = idx1[mt];
            idx1[mt] = idx2[mt];
#pragma unroll
            for (int ks = 0; ks < KS; ks++) raw0[mt][ks] = raw1[mt][ks];
        }
    }

    // epilogue: BN + ReLU, store ms fp16, channel max -> pooled
#pragma unroll
    for (int nt = 0; nt < 4; nt++) {
        int ch = colBase + nt * 16 + ln;
        float s = bns[nt * 16 + ln], bb = bnb[nt * 16 + ln];
        float cmax = 0.f;
#pragma unroll
        for (int mt = 0; mt < 4; mt++)
#pragma unroll
            for (int r = 0; r < 4; r++) {
                int n = n0 + mt * 16 + q * 4 + r;   // always < NPAD
                float v = fmaxf(acc[mt][nt][r] * s + bb, 0.f);
                msf[(long)n * 192 + ch] = f2h(v);
                if (n < N_PTS) cmax = fmaxf(cmax, v);
            }
        cmax = fmaxf(cmax, __shfl_xor(cmax, 16));
        cmax = fmaxf(cmax, __shfl_xor(cmax, 32));
        if (q == 0) atomicMax((int*)(pooled + ch), __float_as_int(cmax));
    }
}

__global__ __launch_bounds__(256) void k_conv(
    const f16* __restrict__ featf, const f16* __restrict__ hf,
    const f16* __restrict__ Wt1, const f16* __restrict__ Wt2b, const f16* __restrict__ Wt3,
    const int* __restrict__ nbr1, const int* __restrict__ nbr2,
    const float* __restrict__ bn1_s, const float* __restrict__ bn1_b,
    const float* __restrict__ bn2b_s, const float* __restrict__ bn2b_b,
    const float* __restrict__ bn3_s, const float* __restrict__ bn3_b,
    f16* __restrict__ msf, float* __restrict__ pooled)
{
    int lane = threadIdx.x & 63, wave = threadIdx.x >> 6;
    int n0 = (blockIdx.x * 4 + wave) * 64;
    conv_path<64>(featf, Wt1,  nbr1, lane, n0, bn1_s,  bn1_b,  msf, 0,   pooled);
    conv_path<32>(hf,    Wt2b, nbr1, lane, n0, bn2b_s, bn2b_b, msf, 64,  pooled);
    conv_path<64>(featf, Wt3,  nbr2, lane, n0, bn3_s,  bn3_b,  msf, 128, pooled);
}

// ---------------------------------------------------------------------------
// attention MLP (1 block) + fold attn*Wf -> Wfst[d][j] fp16
// A1_w: [192,16], A2_w: [16,192]  (COUT//4 == 16)
// ---------------------------------------------------------------------------
__global__ __launch_bounds__(256) void k_attn(
    const float* __restrict__ pooled,
    const float* __restrict__ A1w, const float* __restrict__ A1b,
    const float* __restrict__ A2w, const float* __restrict__ A2b,
    const float* __restrict__ Wf, f16* __restrict__ Wfst)
{
    __shared__ float sp[192], sa1[16], sattn[192];
    int t = threadIdx.x;
    if (t < 192) sp[t] = pooled[t];
    __syncthreads();
    if (t < 16) {
        float acc = A1b[t];
        for (int i = 0; i < 192; i++) acc += sp[i] * A1w[i * 16 + t];
        sa1[t] = fmaxf(acc, 0.f);
    }
    __syncthreads();
    if (t < 192) {
        float acc = A2b[t];
        for (int i = 0; i < 16; i++) acc += sa1[i] * A2w[i * 192 + t];
        sattn[t] = 1.f / (1.f + expf(-acc));
    }
    __syncthreads();
    for (int i = t; i < 192 * 64; i += 256) {
        int d = i / 192, j = i % 192;
        Wfst[i] = f2h(Wf[j * 64 + d] * sattn[j]);
    }
}

// ---------------------------------------------------------------------------
// fusion: out = relu(bnf( ms @ (attn*Wf) ))  fp32 out.  Direct loads, no LDS.
// ---------------------------------------------------------------------------
__global__ __launch_bounds__(256) void k_fuse(
    const f16* __restrict__ msf, const f16* __restrict__ Wfst,
    const float* __restrict__ sf, const float* __restrict__ bf_,
    float* __restrict__ out)
{
    int lane = threadIdx.x & 63, wave = threadIdx.x >> 6;
    int n0 = (blockIdx.x * 4 + wave) * 64;
    int ln = lane & 15, q = lane >> 4;
    f32x4 acc[4][4];
    for (int mt = 0; mt < 4; mt++) for (int nt = 0; nt < 4; nt++)
        acc[mt][nt] = (f32x4){0.f, 0.f, 0.f, 0.f};
#pragma unroll
    for (int kt = 0; kt < 6; kt++) {
        f16x8 a[4];
#pragma unroll
        for (int mt = 0; mt < 4; mt++)
            a[mt] = *(const f16x8*)(msf + (long)(n0 + mt * 16 + ln) * 192 + kt * 32 + q * 8);
#pragma unroll
        for (int nt = 0; nt < 4; nt++) {
            f16x8 b = *(const f16x8*)(Wfst + ((nt * 16 + ln) * 192 + kt * 32 + q * 8));
#pragma unroll
            for (int mt = 0; mt < 4; mt++)
                acc[mt][nt] = __builtin_amdgcn_mfma_f32_16x16x32_f16(a[mt], b, acc[mt][nt], 0, 0, 0);
        }
    }
#pragma unroll
    for (int nt = 0; nt < 4; nt++) {
        int ch = nt * 16 + ln;
        float s = sf[ch], bb = bf_[ch];
#pragma unroll
        for (int mt = 0; mt < 4; mt++)
#pragma unroll
            for (int r = 0; r < 4; r++) {
                int n = n0 + mt * 16 + q * 4 + r;
                if (n < N_PTS)
                    out[(long)n * 64 + ch] = fmaxf(acc[mt][nt][r] * s + bb, 0.f);
            }
    }
}

// ---------------------------------------------------------------------------
extern "C" void kernel_launch(void* const* d_in, const int* in_sizes, int n_in,
                              void* d_out, int out_size, void* d_ws, size_t ws_size,
                              hipStream_t stream)
{
    const float* features = (const float*)d_in[0];
    const float* W1     = (const float*)d_in[1];
    const float* bn1_s  = (const float*)d_in[2];
    const float* bn1_b  = (const float*)d_in[3];
    const float* W2a    = (const float*)d_in[4];
    const float* bn2a_s = (const float*)d_in[5];
    const float* bn2a_b = (const float*)d_in[6];
    const float* W2b    = (const float*)d_in[7];
    const float* bn2b_s = (const float*)d_in[8];
    const float* bn2b_b = (const float*)d_in[9];
    const float* W3     = (const float*)d_in[10];
    const float* bn3_s  = (const float*)d_in[11];
    const float* bn3_b  = (const float*)d_in[12];
    const float* A1w    = (const float*)d_in[13];
    const float* A1b    = (const float*)d_in[14];
    const float* A2w    = (const float*)d_in[15];
    const float* A2b    = (const float*)d_in[16];
    const float* Wf     = (const float*)d_in[17];
    const float* bnf_s  = (const float*)d_in[18];
    const float* bnf_b  = (const float*)d_in[19];
    const int*   nbr1   = (const int*)d_in[20];
    const int*   nbr2   = (const int*)d_in[21];

    char* ws = (char*)d_ws;
    size_t off = 0;
    f16* featf = (f16*)(ws + off); off += (size_t)NPAD * 64 * 2;
    f16* hf    = (f16*)(ws + off); off += (size_t)NPAD * 32 * 2;
    f16* msf   = (f16*)(ws + off); off += (size_t)NPAD * 192 * 2;
    f16* Wt1   = (f16*)(ws + off); off += 9 * 64 * 64 * 2;
    f16* Wt3   = (f16*)(ws + off); off += 9 * 64 * 64 * 2;
    f16* Wt2b  = (f16*)(ws + off); off += 9 * 32 * 64 * 2;
    f16* Wt2a  = (f16*)(ws + off); off += 32 * 64 * 2;
    f16* Wfst  = (f16*)(ws + off); off += 192 * 64 * 2;
    float* pooled = (float*)(ws + off); off += 256 * 4;

    hipMemsetAsync(pooled, 0, 192 * sizeof(float), stream);

    const long FV = (long)NPAD * 8;
    long prep_threads = FV + 94208;
    int prep_blocks = (int)((prep_threads + 255) / 256);
    k_prep<<<prep_blocks, 256, 0, stream>>>(features, W1, W2a, W2b, W3,
                                            featf, Wt1, Wt2a, Wt2b, Wt3);
    k_bottleneck<<<NPAD / 256, 256, 0, stream>>>(featf, Wt2a, bn2a_s, bn2a_b, hf);
    k_conv<<<NPAD / 256, 256, 0, stream>>>(featf, hf, Wt1, Wt2b, Wt3, nbr1, nbr2,
                                           bn1_s, bn1_b, bn2b_s, bn2b_b, bn3_s, bn3_b,
                                           msf, pooled);
    k_attn<<<1, 256, 0, stream>>>(pooled, A1w, A1b, A2w, A2b, Wf, Wfst);
    k_fuse<<<NPAD / 256, 256, 0, stream>>>(msf, Wfst, bnf_s, bnf_b, (float*)d_out);
}

// Round 4
// 517.154 us; speedup vs baseline: 1.5296x; 1.1576x over previous
//
#include <hip/hip_runtime.h>

#define N_PTS 300000
#define NPAD  300032   // 1172 * 256
#define NTILES (NPAD / 64)          // 4688 64-pt tiles
#define NUNITS (NTILES * 3)         // 14064 (tile, path) units

typedef _Float16 f16;
typedef _Float16 f16x8 __attribute__((ext_vector_type(8)));
typedef float    f32x4 __attribute__((ext_vector_type(4)));

__device__ __forceinline__ f16 f2h(float x) { return (f16)x; }

union u4f16 { uint4 u; f16x8 h; };

// ---------------------------------------------------------------------------
// prep: features -> fp16 (vectorized, zero-padded tail rows), weights -> fp16
// transposed.  Wt1/Wt3: [k][d][c]; Wt2b: [k][d][c2]; Wt2a: [d2][c]
// ---------------------------------------------------------------------------
__global__ __launch_bounds__(256) void k_prep(
    const float* __restrict__ feat, const float* __restrict__ W1,
    const float* __restrict__ W2a,  const float* __restrict__ W2b,
    const float* __restrict__ W3,
    f16* __restrict__ featf, f16* __restrict__ Wt1, f16* __restrict__ Wt2a,
    f16* __restrict__ Wt2b, f16* __restrict__ Wt3)
{
    long i = (long)blockIdx.x * 256 + threadIdx.x;
    const long FV = (long)NPAD * 8;          // 8-element chunks of features
    if (i < FV) {
        long n = i >> 3; int c8 = (int)(i & 7) * 8;
        u4f16 v;
        if (n < N_PTS) {
            const float* p = feat + n * 64 + c8;
#pragma unroll
            for (int j = 0; j < 8; j++) v.h[j] = f2h(p[j]);
        } else {
            v.u = make_uint4(0u, 0u, 0u, 0u);
        }
        *(uint4*)(featf + n * 64 + c8) = v.u;
    } else {
        int j = (int)(i - FV);
        if (j < 36864) {                       // Wt1
            int k = j >> 12, rem = j & 4095, d = rem >> 6, c = rem & 63;
            Wt1[j] = f2h(W1[(k << 12) + (c << 6) + d]);
        } else if (j < 73728) {                // Wt3
            int jj = j - 36864;
            int k = jj >> 12, rem = jj & 4095, d = rem >> 6, c = rem & 63;
            Wt3[jj] = f2h(W3[(k << 12) + (c << 6) + d]);
        } else if (j < 73728 + 18432) {        // Wt2b [k][d][c2]
            int jj = j - 73728;
            int k = jj >> 11, rem = jj & 2047, d = rem >> 5, c2 = rem & 31;
            Wt2b[jj] = f2h(W2b[k * 2048 + c2 * 64 + d]);
        } else if (j < 73728 + 18432 + 2048) { // Wt2a [d2][c]
            int jj = j - 73728 - 18432;
            int d2 = jj >> 6, c = jj & 63;
            Wt2a[jj] = f2h(W2a[c * 32 + d2]);
        }
    }
}

// ---------------------------------------------------------------------------
// bottleneck: h = relu(bn2a(feat @ W2a))  [N,32] fp16.  64 pts/wave.
// ---------------------------------------------------------------------------
__global__ __launch_bounds__(256) void k_bottleneck(
    const f16* __restrict__ featf, const f16* __restrict__ Wt2a,
    const float* __restrict__ s2a, const float* __restrict__ b2a,
    f16* __restrict__ hf)
{
    int lane = threadIdx.x & 63, wave = threadIdx.x >> 6;
    int n0 = (blockIdx.x * 4 + wave) * 64;
    int ln = lane & 15, q = lane >> 4;
    f32x4 acc[4][2];
    for (int mt = 0; mt < 4; mt++) for (int nt = 0; nt < 2; nt++)
        acc[mt][nt] = (f32x4){0.f, 0.f, 0.f, 0.f};
#pragma unroll
    for (int ks = 0; ks < 2; ks++) {
        f16x8 a[4];
#pragma unroll
        for (int mt = 0; mt < 4; mt++)
            a[mt] = *(const f16x8*)(featf + ((n0 + mt * 16 + ln) * 64 + ks * 32 + q * 8));
#pragma unroll
        for (int nt = 0; nt < 2; nt++) {
            f16x8 b = *(const f16x8*)(Wt2a + ((nt * 16 + ln) * 64 + ks * 32 + q * 8));
#pragma unroll
            for (int mt = 0; mt < 4; mt++)
                acc[mt][nt] = __builtin_amdgcn_mfma_f32_16x16x32_f16(a[mt], b, acc[mt][nt], 0, 0, 0);
        }
    }
#pragma unroll
    for (int nt = 0; nt < 2; nt++) {
        int ch = nt * 16 + ln;
        float s = s2a[ch], bb = b2a[ch];
#pragma unroll
        for (int mt = 0; mt < 4; mt++)
#pragma unroll
            for (int r = 0; r < 4; r++) {
                int n = n0 + mt * 16 + q * 4 + r;
                if (n < N_PTS)
                    hf[n * 32 + ch] = f2h(fmaxf(acc[mt][nt][r] * s + bb, 0.f));
            }
    }
}

// ---------------------------------------------------------------------------
// sparse-conv path, direct gather, ALL idx upfront + depth-2 row pipeline.
// One wave handles one (64-pt tile, path) unit: 9 taps, uniform pipeline.
// ---------------------------------------------------------------------------
template <int CIN>
__device__ __forceinline__ void loadrows(
    uint4 (&dst)[4][CIN / 32], const int (&idx)[4],
    const f16* __restrict__ src, int q)
{
#pragma unroll
    for (int mt = 0; mt < 4; mt++) {
        long b = (long)(idx[mt] < 0 ? 0 : idx[mt]) * CIN;
#pragma unroll
        for (int ks = 0; ks < CIN / 32; ks++)
            dst[mt][ks] = *(const uint4*)(src + b + ks * 32 + q * 8);
    }
}

template <int CIN>
__device__ __forceinline__ void conv_path(
    const f16* __restrict__ src, const f16* __restrict__ Wt,
    const int* __restrict__ nbr,
    int lane, int n0,
    const float* __restrict__ bns, const float* __restrict__ bnb,
    f16* __restrict__ msf, int colBase, float* __restrict__ pooled)
{
    constexpr int KS = CIN / 32;
    int ln = lane & 15, q = lane >> 4;

    // 1) all 9 taps' neighbor indices issued upfront (coalesced dword loads)
    int idx[9][4];
#pragma unroll
    for (int k = 0; k < 9; k++) {
        const int* nb = nbr + k * N_PTS;
#pragma unroll
        for (int mt = 0; mt < 4; mt++) {
            int nn = n0 + mt * 16 + ln;
            idx[k][mt] = (nn < N_PTS) ? nb[nn] : -1;
        }
    }

    f32x4 acc[4][4];
    for (int mt = 0; mt < 4; mt++) for (int nt = 0; nt < 4; nt++)
        acc[mt][nt] = (f32x4){0.f, 0.f, 0.f, 0.f};

    // 2) depth-2 row-gather pipeline (3 rotating buffers)
    uint4 raw[3][4][KS];
    loadrows<CIN>(raw[0], idx[0], src, q);
    loadrows<CIN>(raw[1], idx[1], src, q);

#pragma unroll
    for (int k = 0; k < 9; k++) {
        if (k + 2 < 9) loadrows<CIN>(raw[(k + 2) % 3], idx[k + 2], src, q);
        // consume tap k: zero-select then MFMA
        f16x8 a[4][KS];
#pragma unroll
        for (int mt = 0; mt < 4; mt++)
#pragma unroll
            for (int ks = 0; ks < KS; ks++) {
                u4f16 v; v.u = raw[k % 3][mt][ks];
                if (idx[k][mt] < 0) v.u = make_uint4(0u, 0u, 0u, 0u);
                a[mt][ks] = v.h;
            }
        const f16* Wk = Wt + k * CIN * 64;
#pragma unroll
        for (int ks = 0; ks < KS; ks++)
#pragma unroll
            for (int nt = 0; nt < 4; nt++) {
                f16x8 b = *(const f16x8*)(Wk + ((nt * 16 + ln) * CIN + ks * 32 + q * 8));
#pragma unroll
                for (int mt = 0; mt < 4; mt++)
                    acc[mt][nt] = __builtin_amdgcn_mfma_f32_16x16x32_f16(a[mt][ks], b, acc[mt][nt], 0, 0, 0);
            }
    }

    // epilogue: BN + ReLU, store ms fp16, channel max -> pooled
#pragma unroll
    for (int nt = 0; nt < 4; nt++) {
        int ch = colBase + nt * 16 + ln;
        float s = bns[nt * 16 + ln], bb = bnb[nt * 16 + ln];
        float cmax = 0.f;
#pragma unroll
        for (int mt = 0; mt < 4; mt++)
#pragma unroll
            for (int r = 0; r < 4; r++) {
                int n = n0 + mt * 16 + q * 4 + r;   // always < NPAD
                float v = fmaxf(acc[mt][nt][r] * s + bb, 0.f);
                msf[(long)n * 192 + ch] = f2h(v);
                if (n < N_PTS) cmax = fmaxf(cmax, v);
            }
        cmax = fmaxf(cmax, __shfl_xor(cmax, 16));
        cmax = fmaxf(cmax, __shfl_xor(cmax, 32));
        if (q == 0) atomicMax((int*)(pooled + ch), __float_as_int(cmax));
    }
}

__global__ __launch_bounds__(256) void k_conv(
    const f16* __restrict__ featf, const f16* __restrict__ hf,
    const f16* __restrict__ Wt1, const f16* __restrict__ Wt2b, const f16* __restrict__ Wt3,
    const int* __restrict__ nbr1, const int* __restrict__ nbr2,
    const float* __restrict__ bn1_s, const float* __restrict__ bn1_b,
    const float* __restrict__ bn2b_s, const float* __restrict__ bn2b_b,
    const float* __restrict__ bn3_s, const float* __restrict__ bn3_b,
    f16* __restrict__ msf, float* __restrict__ pooled)
{
    int lane = threadIdx.x & 63, wave = threadIdx.x >> 6;
    int u = blockIdx.x * 4 + wave;       // (tile, path) unit; grid covers exactly
    int tile = u / 3, path = u - tile * 3;
    int n0 = tile * 64;
    if (path == 0)
        conv_path<64>(featf, Wt1,  nbr1, lane, n0, bn1_s,  bn1_b,  msf, 0,   pooled);
    else if (path == 1)
        conv_path<32>(hf,    Wt2b, nbr1, lane, n0, bn2b_s, bn2b_b, msf, 64,  pooled);
    else
        conv_path<64>(featf, Wt3,  nbr2, lane, n0, bn3_s,  bn3_b,  msf, 128, pooled);
}

// ---------------------------------------------------------------------------
// attention MLP (1 block) + fold attn*Wf -> Wfst[d][j] fp16
// A1_w: [192,16], A2_w: [16,192]  (COUT//4 == 16)
// ---------------------------------------------------------------------------
__global__ __launch_bounds__(256) void k_attn(
    const float* __restrict__ pooled,
    const float* __restrict__ A1w, const float* __restrict__ A1b,
    const float* __restrict__ A2w, const float* __restrict__ A2b,
    const float* __restrict__ Wf, f16* __restrict__ Wfst)
{
    __shared__ float sp[192], sa1[16], sattn[192];
    int t = threadIdx.x;
    if (t < 192) sp[t] = pooled[t];
    __syncthreads();
    if (t < 16) {
        float acc = A1b[t];
        for (int i = 0; i < 192; i++) acc += sp[i] * A1w[i * 16 + t];
        sa1[t] = fmaxf(acc, 0.f);
    }
    __syncthreads();
    if (t < 192) {
        float acc = A2b[t];
        for (int i = 0; i < 16; i++) acc += sa1[i] * A2w[i * 192 + t];
        sattn[t] = 1.f / (1.f + expf(-acc));
    }
    __syncthreads();
    for (int i = t; i < 192 * 64; i += 256) {
        int d = i / 192, j = i % 192;
        Wfst[i] = f2h(Wf[j * 64 + d] * sattn[j]);
    }
}

// ---------------------------------------------------------------------------
// fusion: out = relu(bnf( ms @ (attn*Wf) ))  fp32 out.
// All A-loads issued upfront (one fill stall); B from L1 in-loop.
// ---------------------------------------------------------------------------
__global__ __launch_bounds__(256) void k_fuse(
    const f16* __restrict__ msf, const f16* __restrict__ Wfst,
    const float* __restrict__ sf, const float* __restrict__ bf_,
    float* __restrict__ out)
{
    int lane = threadIdx.x & 63, wave = threadIdx.x >> 6;
    int n0 = (blockIdx.x * 4 + wave) * 64;
    int ln = lane & 15, q = lane >> 4;

    uint4 araw[6][4];
#pragma unroll
    for (int kt = 0; kt < 6; kt++)
#pragma unroll
        for (int mt = 0; mt < 4; mt++)
            araw[kt][mt] = *(const uint4*)(msf + (long)(n0 + mt * 16 + ln) * 192 + kt * 32 + q * 8);

    f32x4 acc[4][4];
    for (int mt = 0; mt < 4; mt++) for (int nt = 0; nt < 4; nt++)
        acc[mt][nt] = (f32x4){0.f, 0.f, 0.f, 0.f};

#pragma unroll
    for (int kt = 0; kt < 6; kt++) {
#pragma unroll
        for (int nt = 0; nt < 4; nt++) {
            f16x8 b = *(const f16x8*)(Wfst + ((nt * 16 + ln) * 192 + kt * 32 + q * 8));
#pragma unroll
            for (int mt = 0; mt < 4; mt++) {
                u4f16 v; v.u = araw[kt][mt];
                acc[mt][nt] = __builtin_amdgcn_mfma_f32_16x16x32_f16(v.h, b, acc[mt][nt], 0, 0, 0);
            }
        }
    }
#pragma unroll
    for (int nt = 0; nt < 4; nt++) {
        int ch = nt * 16 + ln;
        float s = sf[ch], bb = bf_[ch];
#pragma unroll
        for (int mt = 0; mt < 4; mt++)
#pragma unroll
            for (int r = 0; r < 4; r++) {
                int n = n0 + mt * 16 + q * 4 + r;
                if (n < N_PTS)
                    out[(long)n * 64 + ch] = fmaxf(acc[mt][nt][r] * s + bb, 0.f);
            }
    }
}

// ---------------------------------------------------------------------------
extern "C" void kernel_launch(void* const* d_in, const int* in_sizes, int n_in,
                              void* d_out, int out_size, void* d_ws, size_t ws_size,
                              hipStream_t stream)
{
    const float* features = (const float*)d_in[0];
    const float* W1     = (const float*)d_in[1];
    const float* bn1_s  = (const float*)d_in[2];
    const float* bn1_b  = (const float*)d_in[3];
    const float* W2a    = (const float*)d_in[4];
    const float* bn2a_s = (const float*)d_in[5];
    const float* bn2a_b = (const float*)d_in[6];
    const float* W2b    = (const float*)d_in[7];
    const float* bn2b_s = (const float*)d_in[8];
    const float* bn2b_b = (const float*)d_in[9];
    const float* W3     = (const float*)d_in[10];
    const float* bn3_s  = (const float*)d_in[11];
    const float* bn3_b  = (const float*)d_in[12];
    const float* A1w    = (const float*)d_in[13];
    const float* A1b    = (const float*)d_in[14];
    const float* A2w    = (const float*)d_in[15];
    const float* A2b    = (const float*)d_in[16];
    const float* Wf     = (const float*)d_in[17];
    const float* bnf_s  = (const float*)d_in[18];
    const float* bnf_b  = (const float*)d_in[19];
    const int*   nbr1   = (const int*)d_in[20];
    const int*   nbr2   = (const int*)d_in[21];

    char* ws = (char*)d_ws;
    size_t off = 0;
    f16* featf = (f16*)(ws + off); off += (size_t)NPAD * 64 * 2;
    f16* hf    = (f16*)(ws + off); off += (size_t)NPAD * 32 * 2;
    f16* msf   = (f16*)(ws + off); off += (size_t)NPAD * 192 * 2;
    f16* Wt1   = (f16*)(ws + off); off += 9 * 64 * 64 * 2;
    f16* Wt3   = (f16*)(ws + off); off += 9 * 64 * 64 * 2;
    f16* Wt2b  = (f16*)(ws + off); off += 9 * 32 * 64 * 2;
    f16* Wt2a  = (f16*)(ws + off); off += 32 * 64 * 2;
    f16* Wfst  = (f16*)(ws + off); off += 192 * 64 * 2;
    float* pooled = (float*)(ws + off); off += 256 * 4;

    hipMemsetAsync(pooled, 0, 192 * sizeof(float), stream);

    const long FV = (long)NPAD * 8;
    long prep_threads = FV + 94208;
    int prep_blocks = (int)((prep_threads + 255) / 256);
    k_prep<<<prep_blocks, 256, 0, stream>>>(features, W1, W2a, W2b, W3,
                                            featf, Wt1, Wt2a, Wt2b, Wt3);
    k_bottleneck<<<NPAD / 256, 256, 0, stream>>>(featf, Wt2a, bn2a_s, bn2a_b, hf);
    k_conv<<<NUNITS / 4, 256, 0, stream>>>(featf, hf, Wt1, Wt2b, Wt3, nbr1, nbr2,
                                           bn1_s, bn1_b, bn2b_s, bn2b_b, bn3_s, bn3_b,
                                           msf, pooled);
    k_attn<<<1, 256, 0, stream>>>(pooled, A1w, A1b, A2w, A2b, Wf, Wfst);
    k_fuse<<<NPAD / 256, 256, 0, stream>>>(msf, Wfst, bnf_s, bnf_b, (float*)d_out);
}